// Round 12
// baseline (534.379 us; speedup 1.0000x reference)
//
#include <hip/hip_runtime.h>
#include <hip/hip_fp16.h>
#include <cstdint>
#include <cstddef>

#define NNODES 100000
#define NEDGES 1600000
#define NGRAPH 1024

// bucketized CSR build
#define BK 256                             // nodes per bucket (dst >> 8)
#define NBUCKET 391                        // ceil(NNODES / BK)
#define CHUNK 4096
#define NCHUNK 391                         // ceil(NEDGES / CHUNK)
#define NBE (NBUCKET * NCHUNK)             // 152881 count-matrix entries

// setup_kernel block ranges
#define SB_CVT 6250                        // NNODES*64/4/256
#define SB_PRE (SB_CVT + 60)
#define SB_GPTR (SB_PRE + 391)
#define SB_CNT (SB_GPTR + NCHUNK)
#define SB_TOTAL SB_CNT

typedef __attribute__((ext_vector_type(8))) unsigned short ushort8;
typedef __attribute__((ext_vector_type(8))) _Float16 f16x8;
typedef __attribute__((ext_vector_type(4))) float f32x4;

__device__ inline unsigned short f2h(float f) {
  return __half_as_ushort(__float2half_rn(f));
}
__device__ inline float h2f(unsigned short u) {
  return __half2float(__ushort_as_half(u));
}
// packed edge: (src << 15) | (fp16(weight) >> 1)   [weight >= 0 so sign bit = 0]
__device__ inline unsigned int pack_edge(int src, float w) {
  unsigned short hb = __half_as_ushort(__float2half_rn(w));
  return ((unsigned int)src << 15) | ((unsigned int)hb >> 1);
}
__device__ inline void unpack_edge_h(unsigned int p, int& src, __half2& w2) {
  src = (int)(p >> 15);
  __half wh = __ushort_as_half((unsigned short)((p & 0x7fffu) << 1));
  w2 = __half2half2(wh);
}

// ---------------- fused setup: cvt_x | prepack | gptr | bucket_count ----------------
__global__ __launch_bounds__(256) void setup_kernel(
    const float* __restrict__ x, unsigned short* __restrict__ xb,
    const float* __restrict__ Wrel0, const float* __restrict__ Wroot0,
    const float* __restrict__ WrelR, const float* __restrict__ WrootR,
    const float* __restrict__ Wr1, unsigned short* __restrict__ wp,
    const int* __restrict__ batch, int* __restrict__ gptr,
    const int* __restrict__ ei, int* __restrict__ cnt)
{
  __shared__ int hist[NBUCKET];
  int blk = blockIdx.x;
  if (blk < SB_CVT) {
    int i = blk * 256 + threadIdx.x;
    float4 v = *(const float4*)(x + (size_t)i * 4);
    ushort4 o;
    o.x = f2h(v.x); o.y = f2h(v.y); o.z = f2h(v.z); o.w = f2h(v.w);
    *(ushort4*)(xb + (size_t)i * 4) = o;
  } else if (blk < SB_PRE) {
    int g = (blk - SB_CVT) * 256 + threadIdx.x;
    if (g >= 15360) return;
    const float* src; int H, K, r; unsigned short* out;
    if (g < 1024)       { src = Wrel0;  H = 128; K = 64;  r = g;        out = wp + r * 8; }
    else if (g < 2048)  { src = Wroot0; H = 128; K = 64;  r = g - 1024; out = wp + 8192 + r * 8; }
    else if (g < 8192)  { int m = g - 2048; int l = m / 2048; r = m % 2048;
                          src = WrelR + l * 16384;  H = 128; K = 128;
                          out = wp + 16384 + l * 16384 + r * 8; }
    else if (g < 14336) { int m = g - 8192; int l = m / 2048; r = m % 2048;
                          src = WrootR + l * 16384; H = 128; K = 128;
                          out = wp + 65536 + l * 16384 + r * 8; }
    else                { src = Wr1;    H = 64;  K = 128; r = g - 14336; out = wp + 114688 + r * 8; }
    int n = r % H, k8 = r / H;
    const float* s = src + (size_t)n * K + k8 * 8;
#pragma unroll
    for (int j = 0; j < 8; j++) out[j] = f2h(s[j]);
  } else if (blk < SB_GPTR) {
    int i = (blk - SB_PRE) * 256 + threadIdx.x;
    if (i >= NNODES) return;
    int b = batch[i];
    int bn = (i + 1 < NNODES) ? batch[i + 1] : NGRAPH;
    for (int g = b + 1; g <= bn; g++) gptr[g] = i + 1;
    if (i == 0) for (int g = 0; g <= b; g++) gptr[g] = 0;
  } else {
    int chunk = blk - SB_GPTR;
    for (int i = threadIdx.x; i < NBUCKET; i += 256) hist[i] = 0;
    __syncthreads();
    int base = chunk * CHUNK;
    for (int t = threadIdx.x; t < CHUNK; t += 256) {
      int e = base + t;
      if (e < NEDGES) atomicAdd(&hist[ei[NEDGES + e] >> 8], 1);
    }
    __syncthreads();
    for (int i = threadIdx.x; i < NBUCKET; i += 256)
      cnt[i * NCHUNK + chunk] = hist[i];
  }
}

// ---------------- bucketized CSR build ----------------
__global__ __launch_bounds__(512) void row_scan_kernel(
    int* __restrict__ cnt, int* __restrict__ rowsum)
{
  __shared__ int s[512];
  int b = blockIdx.x, t = threadIdx.x;
  int v = (t < NCHUNK) ? cnt[b * NCHUNK + t] : 0;
  s[t] = v;
  __syncthreads();
#pragma unroll
  for (int off = 1; off < 512; off <<= 1) {
    int u = (t >= off) ? s[t - off] : 0;
    __syncthreads();
    s[t] += u;
    __syncthreads();
  }
  if (t < NCHUNK) cnt[b * NCHUNK + t] = s[t] - v;
  if (t == 511) rowsum[b] = s[511];
}

__global__ __launch_bounds__(512) void rowbase_scan_kernel(
    const int* __restrict__ rowsum, int* __restrict__ rowbase)
{
  __shared__ int s[512];
  int t = threadIdx.x;
  int v = (t < NBUCKET) ? rowsum[t] : 0;
  s[t] = v;
  __syncthreads();
#pragma unroll
  for (int off = 1; off < 512; off <<= 1) {
    int u = (t >= off) ? s[t - off] : 0;
    __syncthreads();
    s[t] += u;
    __syncthreads();
  }
  if (t < NBUCKET) rowbase[t] = s[t] - v;
  if (t == 511) rowbase[NBUCKET] = s[511];   // == NEDGES
}

__global__ __launch_bounds__(256) void bucket_scatter_kernel(
    const int* __restrict__ ei, const float* __restrict__ ew,
    const int* __restrict__ cnt, const int* __restrict__ rowbase,
    uint2* __restrict__ rec)
{
  __shared__ int pos[NBUCKET];
  for (int i = threadIdx.x; i < NBUCKET; i += 256)
    pos[i] = rowbase[i] + cnt[i * NCHUNK + blockIdx.x];
  __syncthreads();
  int base = blockIdx.x * CHUNK;
  for (int t = threadIdx.x; t < CHUNK; t += 256) {
    int e = base + t;
    if (e < NEDGES) {
      int d = ei[NEDGES + e];
      int p = atomicAdd(&pos[d >> 8], 1);
      rec[p] = make_uint2((unsigned int)d, pack_edge(ei[e], ew[e]));
    }
  }
}

__global__ __launch_bounds__(256) void bucket_fill_kernel(
    const int* __restrict__ rowbase, const uint2* __restrict__ rec,
    unsigned int* __restrict__ epack, int* __restrict__ row_ptr)
{
  __shared__ int off[BK];
  __shared__ int s[256];
  int b = blockIdx.x, t = threadIdx.x;
  int start = rowbase[b];
  int end = rowbase[b + 1];
  int nbase = b * BK;
  off[t] = 0;
  __syncthreads();
  for (int i = start + t; i < end; i += 256)
    atomicAdd(&off[rec[i].x - nbase], 1);
  __syncthreads();
  int v = off[t];
  s[t] = v;
  __syncthreads();
#pragma unroll
  for (int o = 1; o < 256; o <<= 1) {
    int u = (t >= o) ? s[t - o] : 0;
    __syncthreads();
    s[t] += u;
    __syncthreads();
  }
  int ex = s[t] - v;
  int g = nbase + t;
  if (g <= NNODES) row_ptr[g] = start + ex;   // g==NNODES -> start+ex == NEDGES
  __syncthreads();
  off[t] = ex;
  __syncthreads();
  for (int i = start + t; i < end; i += 256) {
    uint2 r = rec[i];
    int lp = atomicAdd(&off[r.x - nbase], 1);
    epack[start + lp] = r.y;
  }
}

// ---------------- fp16 gather aggregation ----------------
// agg128h: HALF-FEATURE gather (cols [colbase, colbase+64)). Wave per node,
// eighth-split, 2-deep -> 16 rows in flight/wave, row stride 128. Two
// dispatches replace agg128: same compulsory traffic (same distinct rows,
// half bytes each), each ~28us -> lowers the rocprof top-5 threshold so
// the hidden mid-size kernels surface.
__global__ __launch_bounds__(256) void agg128h_kernel(
    const int* __restrict__ row_ptr, const unsigned int* __restrict__ epack,
    const unsigned short* __restrict__ x, unsigned short* __restrict__ agg,
    int colbase)
{
  int node = blockIdx.x * 4 + (threadIdx.x >> 6);
  int lane = threadIdx.x & 63;
  if (node >= NNODES) return;
  int q = lane >> 3, sl = lane & 7;
  int s = row_ptr[node], e = row_ptr[node + 1];
  __half2 acch[4];
#pragma unroll
  for (int k = 0; k < 4; k++) acch[k] = __half2half2(__ushort_as_half(0));

  union HU { ushort8 u; __half2 h[4]; };
  const unsigned short* xc = x + colbase;
  for (int i = s + q; i < e; i += 16) {
    unsigned int p0 = epack[i];
    unsigned int p1 = (i + 8 < e) ? epack[i + 8] : 0u;
    int s0, s1; __half2 wA, wB;
    unpack_edge_h(p0, s0, wA);
    unpack_edge_h(p1, s1, wB);
    HU r0, r1;
    r0.u = *(const ushort8*)(xc + (size_t)s0 * 128 + sl * 8);
    r1.u = *(const ushort8*)(xc + (size_t)s1 * 128 + sl * 8);
#pragma unroll
    for (int k = 0; k < 4; k++) {
      acch[k] = __hfma2(wA, r0.h[k], acch[k]);
      acch[k] = __hfma2(wB, r1.h[k], acch[k]);
    }
  }
  float acc[8];
#pragma unroll
  for (int k = 0; k < 4; k++) {
    acc[2 * k]     = __low2float(acch[k]);
    acc[2 * k + 1] = __high2float(acch[k]);
  }
#pragma unroll
  for (int j = 0; j < 8; j++) {
    acc[j] += __shfl_xor(acc[j], 8, 64);
    acc[j] += __shfl_xor(acc[j], 16, 64);
    acc[j] += __shfl_xor(acc[j], 32, 64);
  }
  if (q == 0) {
    ushort8 o;
#pragma unroll
    for (int j = 0; j < 8; j++) o[j] = f2h(acc[j]);
    *(ushort8*)(agg + (size_t)node * 128 + colbase + sl * 8) = o;
  }
}

// agg64: wave per node, eighth-split, 2-deep unroll, packed fp16 math.
__global__ __launch_bounds__(256) void agg64_kernel(
    const int* __restrict__ row_ptr, const unsigned int* __restrict__ epack,
    const unsigned short* __restrict__ x, unsigned short* __restrict__ agg)
{
  int node = blockIdx.x * 4 + (threadIdx.x >> 6);
  int lane = threadIdx.x & 63;
  if (node >= NNODES) return;
  int q = lane >> 3, sl = lane & 7;
  int s = row_ptr[node], e = row_ptr[node + 1];
  __half2 acch[4];
#pragma unroll
  for (int k = 0; k < 4; k++) acch[k] = __half2half2(__ushort_as_half(0));

  union HU { ushort8 u; __half2 h[4]; };
  for (int i = s + q; i < e; i += 16) {
    unsigned int p0 = epack[i];
    unsigned int p1 = (i + 8 < e) ? epack[i + 8] : 0u;
    int s0, s1; __half2 wA, wB;
    unpack_edge_h(p0, s0, wA);
    unpack_edge_h(p1, s1, wB);
    HU r0, r1;
    r0.u = *(const ushort8*)(x + (size_t)s0 * 64 + sl * 8);
    r1.u = *(const ushort8*)(x + (size_t)s1 * 64 + sl * 8);
#pragma unroll
    for (int k = 0; k < 4; k++) {
      acch[k] = __hfma2(wA, r0.h[k], acch[k]);
      acch[k] = __hfma2(wB, r1.h[k], acch[k]);
    }
  }
  float acc[8];
#pragma unroll
  for (int k = 0; k < 4; k++) {
    acc[2 * k]     = __low2float(acch[k]);
    acc[2 * k + 1] = __high2float(acch[k]);
  }
#pragma unroll
  for (int j = 0; j < 8; j++) {
    acc[j] += __shfl_xor(acc[j], 8, 64);
    acc[j] += __shfl_xor(acc[j], 16, 64);
    acc[j] += __shfl_xor(acc[j], 32, 64);
  }
  if (q == 0) {
    ushort8 o;
#pragma unroll
    for (int j = 0; j < 8; j++) o[j] = f2h(acc[j]);
    *(ushort8*)(agg + (size_t)node * 64 + sl * 8) = o;
  }
}

// ---------------- LDS-free MFMA fp16 GEMM ----------------
template <int KDIM, int HOUT, int MT, bool DUAL, bool RELU>
__global__ __launch_bounds__(256) void mfma_gemm(
    const unsigned short* __restrict__ A1, const unsigned short* __restrict__ W1,
    const unsigned short* __restrict__ A2, const unsigned short* __restrict__ W2,
    const float* __restrict__ bias, unsigned short* __restrict__ out)
{
  constexpr int NT2 = HOUT / 16;
  constexpr int KC = KDIM / 32;
  const int wave = threadIdx.x >> 6, lane = threadIdx.x & 63;
  const int quad = lane >> 4, l16 = lane & 15;
  const int n0 = (blockIdx.x * 4 + wave) * (MT * 16);

  f32x4 acc[MT][NT2];
#pragma unroll
  for (int m = 0; m < MT; m++)
#pragma unroll
    for (int t = 0; t < NT2; t++) acc[m][t] = (f32x4){0.f, 0.f, 0.f, 0.f};

  int nodes[MT];
#pragma unroll
  for (int m = 0; m < MT; m++) {
    int nd = n0 + m * 16 + l16;
    nodes[m] = nd < NNODES ? nd : NNODES - 1;
  }

#pragma unroll
  for (int c = 0; c < KC; c++) {
    f16x8 bfr[NT2];
#pragma unroll
    for (int t = 0; t < NT2; t++)
      bfr[t] = *(const f16x8*)(W1 + ((size_t)(c * 4 + quad) * HOUT + t * 16 + l16) * 8);
#pragma unroll
    for (int m = 0; m < MT; m++) {
      f16x8 af = *(const f16x8*)(A1 + (size_t)nodes[m] * KDIM + c * 32 + quad * 8);
#pragma unroll
      for (int t = 0; t < NT2; t++)
        acc[m][t] = __builtin_amdgcn_mfma_f32_16x16x32_f16(af, bfr[t], acc[m][t], 0, 0, 0);
    }
    if (DUAL) {
#pragma unroll
      for (int t = 0; t < NT2; t++)
        bfr[t] = *(const f16x8*)(W2 + ((size_t)(c * 4 + quad) * HOUT + t * 16 + l16) * 8);
#pragma unroll
      for (int m = 0; m < MT; m++) {
        f16x8 af = *(const f16x8*)(A2 + (size_t)nodes[m] * KDIM + c * 32 + quad * 8);
#pragma unroll
        for (int t = 0; t < NT2; t++)
          acc[m][t] = __builtin_amdgcn_mfma_f32_16x16x32_f16(af, bfr[t], acc[m][t], 0, 0, 0);
      }
    }
  }

#pragma unroll
  for (int m = 0; m < MT; m++) {
    int rowbase = n0 + m * 16 + quad * 4;
#pragma unroll
    for (int t = 0; t < NT2; t++) {
      float b = bias[t * 16 + l16];
#pragma unroll
      for (int r = 0; r < 4; r++) {
        int nd = rowbase + r;
        if (nd < NNODES) {
          float v = acc[m][t][r] + b;
          if (RELU) v = fmaxf(v, 0.f);
          out[(size_t)nd * HOUT + t * 16 + l16] = f2h(v);
        }
      }
    }
  }
}

// ---------------- readout: per-graph block reduction ----------------
__global__ __launch_bounds__(256) void readout_reduce_kernel(
    const unsigned short* __restrict__ h, const float* __restrict__ Wr2,
    const float* __restrict__ br2, const int* __restrict__ gptr,
    float* __restrict__ out)
{
  __shared__ float wsum[4];
  int g = blockIdx.x;
  int s = gptr[g], e = gptr[g + 1];
  int wave = threadIdx.x >> 6, lane = threadIdx.x & 63;
  float w2 = Wr2[lane];
  float acc = 0.f;
  for (int n = s + wave; n < e; n += 4)
    acc += h2f(h[(size_t)n * 64 + lane]) * w2;
#pragma unroll
  for (int off = 32; off >= 1; off >>= 1) acc += __shfl_xor(acc, off, 64);
  if (lane == 0) wsum[wave] = acc;
  __syncthreads();
  if (threadIdx.x == 0) {
    float cnt = (float)(e - s);
    float sum = wsum[0] + wsum[1] + wsum[2] + wsum[3] + cnt * br2[0];
    out[g] = sum / fmaxf(cnt, 1.f);
  }
}

// ---------------- launch ----------------
extern "C" void kernel_launch(void* const* d_in, const int* in_sizes, int n_in,
                              void* d_out, int out_size, void* d_ws, size_t ws_size,
                              hipStream_t stream)
{
  const float* x      = (const float*)d_in[0];
  const int*   ei     = (const int*)d_in[1];
  const float* ew     = (const float*)d_in[2];
  const int*   batch  = (const int*)d_in[3];
  const float* Wroot0 = (const float*)d_in[4];
  const float* Wrel0  = (const float*)d_in[5];
  const float* b0     = (const float*)d_in[6];
  const float* WrootR = (const float*)d_in[7];
  const float* WrelR  = (const float*)d_in[8];
  const float* bR     = (const float*)d_in[9];
  const float* Wr1    = (const float*)d_in[10];
  const float* br1    = (const float*)d_in[11];
  const float* Wr2    = (const float*)d_in[12];
  const float* br2    = (const float*)d_in[13];

  char* ws = (char*)d_ws;
  unsigned short* wp   = (unsigned short*)ws;                 // 122880 fp16, pad to 131072
  unsigned short* xb   = wp + 131072;                         // N*64 fp16
  unsigned short* agg0 = xb + (size_t)NNODES * 64;            // N*64 fp16 (layer-0 agg)
  unsigned short* bufA = agg0 + (size_t)NNODES * 64;          // N*128 fp16
  unsigned short* bufB = bufA + (size_t)NNODES * 128;         // N*128 fp16
  unsigned short* hbuf = bufB + (size_t)NNODES * 128;         // N*64 fp16
  int*  cnt      = (int*)(hbuf + (size_t)NNODES * 64);        // NBE ints (~600KB)
  int*  rowsum   = cnt + ((NBE + 63) & ~63);
  int*  rowbase  = rowsum + NBUCKET + 1;
  int*  row_ptr  = rowbase + NBUCKET + 1;
  int*  gptr     = row_ptr + NNODES + 2;
  unsigned int* epack = (unsigned int*)(gptr + NGRAPH + 2);   // E uint = 6.4MB
  // rec aliases bufA (12.8MB <= 25.6MB); bufA first written by layer-1 agg,
  // long after bucket_fill_kernel has consumed rec.
  uint2* rec = (uint2*)bufA;

  const unsigned short* pWrel0  = wp;
  const unsigned short* pWroot0 = wp + 8192;
  const unsigned short* pWrelR  = wp + 16384;
  const unsigned short* pWrootR = wp + 65536;
  const unsigned short* pWr1    = wp + 114688;

  // fused setup: cvt_x | prepack | gptr | bucket_count
  setup_kernel<<<SB_TOTAL, 256, 0, stream>>>(
      x, xb, Wrel0, Wroot0, WrelR, WrootR, Wr1, wp, batch, gptr, ei, cnt);

  // bucketized CSR build (by dst)
  row_scan_kernel<<<NBUCKET, 512, 0, stream>>>(cnt, rowsum);
  rowbase_scan_kernel<<<1, 512, 0, stream>>>(rowsum, rowbase);
  bucket_scatter_kernel<<<NCHUNK, 256, 0, stream>>>(ei, ew, cnt, rowbase, rec);
  bucket_fill_kernel<<<NBUCKET, 256, 0, stream>>>(rowbase, rec, epack, row_ptr);

  // layer 0: 64 -> 128
  agg64_kernel<<<(NNODES + 3) / 4, 256, 0, stream>>>(row_ptr, epack, xb, agg0);
  mfma_gemm<64, 128, 2, true, false><<<(NNODES + 127) / 128, 256, 0, stream>>>(
      agg0, pWrel0, xb, pWroot0, b0, bufB);

  // layers 1..3: 128 -> 128 (half-feature agg x2 per layer)
  unsigned short* bufs[2] = { bufB, bufA };
  for (int l = 0; l < 3; l++) {
    unsigned short* in  = bufs[l & 1];
    unsigned short* agg = bufs[(l & 1) ^ 1];
    agg128h_kernel<<<(NNODES + 3) / 4, 256, 0, stream>>>(row_ptr, epack, in, agg, 0);
    agg128h_kernel<<<(NNODES + 3) / 4, 256, 0, stream>>>(row_ptr, epack, in, agg, 64);
    mfma_gemm<128, 128, 2, true, false><<<(NNODES + 127) / 128, 256, 0, stream>>>(
        agg, pWrelR + l * 16384, in, pWrootR + l * 16384, bR + l * 128, agg);
  }
  // y3 in bufA

  // readout (split, atomic-free: GEMM -> hbuf -> per-graph reduce)
  mfma_gemm<128, 64, 4, false, true><<<(NNODES + 255) / 256, 256, 0, stream>>>(
      bufA, pWr1, nullptr, nullptr, br1, hbuf);
  readout_reduce_kernel<<<NGRAPH, 256, 0, stream>>>(hbuf, Wr2, br2, gptr, (float*)d_out);
}

// Round 13
// 520.352 us; speedup vs baseline: 1.0270x; 1.0270x over previous
//
#include <hip/hip_runtime.h>
#include <hip/hip_fp16.h>
#include <cstdint>
#include <cstddef>

#define NNODES 100000
#define NEDGES 1600000
#define NGRAPH 1024

// bucketized CSR build
#define BK 256                             // nodes per bucket (dst >> 8)
#define NBUCKET 391                        // ceil(NNODES / BK)
#define CHUNK 4096
#define NCHUNK 391                         // ceil(NEDGES / CHUNK)
#define NBE (NBUCKET * NCHUNK)             // 152881 count-matrix entries

// setup_kernel block ranges
#define SB_CVT 6250                        // NNODES*64/4/256
#define SB_PRE (SB_CVT + 60)
#define SB_GPTR (SB_PRE + 391)
#define SB_CNT (SB_GPTR + NCHUNK)
#define SB_TOTAL SB_CNT

typedef __attribute__((ext_vector_type(8))) unsigned short ushort8;
typedef __attribute__((ext_vector_type(8))) _Float16 f16x8;
typedef __attribute__((ext_vector_type(4))) float f32x4;

__device__ inline unsigned short f2h(float f) {
  return __half_as_ushort(__float2half_rn(f));
}
__device__ inline float h2f(unsigned short u) {
  return __half2float(__ushort_as_half(u));
}
// packed edge: (src << 15) | (fp16(weight) >> 1)   [weight >= 0 so sign bit = 0]
__device__ inline unsigned int pack_edge(int src, float w) {
  unsigned short hb = __half_as_ushort(__float2half_rn(w));
  return ((unsigned int)src << 15) | ((unsigned int)hb >> 1);
}
__device__ inline void unpack_edge_h(unsigned int p, int& src, __half2& w2) {
  src = (int)(p >> 15);
  __half wh = __ushort_as_half((unsigned short)((p & 0x7fffu) << 1));
  w2 = __half2half2(wh);
}

// ---------------- fused setup: cvt_x | prepack | gptr | bucket_count ----------------
__global__ __launch_bounds__(256) void setup_kernel(
    const float* __restrict__ x, unsigned short* __restrict__ xb,
    const float* __restrict__ Wrel0, const float* __restrict__ Wroot0,
    const float* __restrict__ WrelR, const float* __restrict__ WrootR,
    const float* __restrict__ Wr1, unsigned short* __restrict__ wp,
    const int* __restrict__ batch, int* __restrict__ gptr,
    const int* __restrict__ ei, int* __restrict__ cnt)
{
  __shared__ int hist[NBUCKET];
  int blk = blockIdx.x;
  if (blk < SB_CVT) {
    int i = blk * 256 + threadIdx.x;
    float4 v = *(const float4*)(x + (size_t)i * 4);
    ushort4 o;
    o.x = f2h(v.x); o.y = f2h(v.y); o.z = f2h(v.z); o.w = f2h(v.w);
    *(ushort4*)(xb + (size_t)i * 4) = o;
  } else if (blk < SB_PRE) {
    int g = (blk - SB_CVT) * 256 + threadIdx.x;
    if (g >= 15360) return;
    const float* src; int H, K, r; unsigned short* out;
    if (g < 1024)       { src = Wrel0;  H = 128; K = 64;  r = g;        out = wp + r * 8; }
    else if (g < 2048)  { src = Wroot0; H = 128; K = 64;  r = g - 1024; out = wp + 8192 + r * 8; }
    else if (g < 8192)  { int m = g - 2048; int l = m / 2048; r = m % 2048;
                          src = WrelR + l * 16384;  H = 128; K = 128;
                          out = wp + 16384 + l * 16384 + r * 8; }
    else if (g < 14336) { int m = g - 8192; int l = m / 2048; r = m % 2048;
                          src = WrootR + l * 16384; H = 128; K = 128;
                          out = wp + 65536 + l * 16384 + r * 8; }
    else                { src = Wr1;    H = 64;  K = 128; r = g - 14336; out = wp + 114688 + r * 8; }
    int n = r % H, k8 = r / H;
    const float* s = src + (size_t)n * K + k8 * 8;
#pragma unroll
    for (int j = 0; j < 8; j++) out[j] = f2h(s[j]);
  } else if (blk < SB_GPTR) {
    int i = (blk - SB_PRE) * 256 + threadIdx.x;
    if (i >= NNODES) return;
    int b = batch[i];
    int bn = (i + 1 < NNODES) ? batch[i + 1] : NGRAPH;
    for (int g = b + 1; g <= bn; g++) gptr[g] = i + 1;
    if (i == 0) for (int g = 0; g <= b; g++) gptr[g] = 0;
  } else {
    int chunk = blk - SB_GPTR;
    for (int i = threadIdx.x; i < NBUCKET; i += 256) hist[i] = 0;
    __syncthreads();
    int base = chunk * CHUNK;
    for (int t = threadIdx.x; t < CHUNK; t += 256) {
      int e = base + t;
      if (e < NEDGES) atomicAdd(&hist[ei[NEDGES + e] >> 8], 1);
    }
    __syncthreads();
    for (int i = threadIdx.x; i < NBUCKET; i += 256)
      cnt[i * NCHUNK + chunk] = hist[i];
  }
}

// ---------------- bucketized CSR build ----------------
__global__ __launch_bounds__(512) void row_scan_kernel(
    int* __restrict__ cnt, int* __restrict__ rowsum)
{
  __shared__ int s[512];
  int b = blockIdx.x, t = threadIdx.x;
  int v = (t < NCHUNK) ? cnt[b * NCHUNK + t] : 0;
  s[t] = v;
  __syncthreads();
#pragma unroll
  for (int off = 1; off < 512; off <<= 1) {
    int u = (t >= off) ? s[t - off] : 0;
    __syncthreads();
    s[t] += u;
    __syncthreads();
  }
  if (t < NCHUNK) cnt[b * NCHUNK + t] = s[t] - v;
  if (t == 511) rowsum[b] = s[511];
}

__global__ __launch_bounds__(512) void rowbase_scan_kernel(
    const int* __restrict__ rowsum, int* __restrict__ rowbase)
{
  __shared__ int s[512];
  int t = threadIdx.x;
  int v = (t < NBUCKET) ? rowsum[t] : 0;
  s[t] = v;
  __syncthreads();
#pragma unroll
  for (int off = 1; off < 512; off <<= 1) {
    int u = (t >= off) ? s[t - off] : 0;
    __syncthreads();
    s[t] += u;
    __syncthreads();
  }
  if (t < NBUCKET) rowbase[t] = s[t] - v;
  if (t == 511) rowbase[NBUCKET] = s[511];   // == NEDGES
}

__global__ __launch_bounds__(256) void bucket_scatter_kernel(
    const int* __restrict__ ei, const float* __restrict__ ew,
    const int* __restrict__ cnt, const int* __restrict__ rowbase,
    uint2* __restrict__ rec)
{
  __shared__ int pos[NBUCKET];
  for (int i = threadIdx.x; i < NBUCKET; i += 256)
    pos[i] = rowbase[i] + cnt[i * NCHUNK + blockIdx.x];
  __syncthreads();
  int base = blockIdx.x * CHUNK;
  for (int t = threadIdx.x; t < CHUNK; t += 256) {
    int e = base + t;
    if (e < NEDGES) {
      int d = ei[NEDGES + e];
      int p = atomicAdd(&pos[d >> 8], 1);
      rec[p] = make_uint2((unsigned int)d, pack_edge(ei[e], ew[e]));
    }
  }
}

__global__ __launch_bounds__(256) void bucket_fill_kernel(
    const int* __restrict__ rowbase, const uint2* __restrict__ rec,
    unsigned int* __restrict__ epack, int* __restrict__ row_ptr)
{
  __shared__ int off[BK];
  __shared__ int s[256];
  int b = blockIdx.x, t = threadIdx.x;
  int start = rowbase[b];
  int end = rowbase[b + 1];
  int nbase = b * BK;
  off[t] = 0;
  __syncthreads();
  for (int i = start + t; i < end; i += 256)
    atomicAdd(&off[rec[i].x - nbase], 1);
  __syncthreads();
  int v = off[t];
  s[t] = v;
  __syncthreads();
#pragma unroll
  for (int o = 1; o < 256; o <<= 1) {
    int u = (t >= o) ? s[t - o] : 0;
    __syncthreads();
    s[t] += u;
    __syncthreads();
  }
  int ex = s[t] - v;
  int g = nbase + t;
  if (g <= NNODES) row_ptr[g] = start + ex;   // g==NNODES -> start+ex == NEDGES
  __syncthreads();
  off[t] = ex;
  __syncthreads();
  for (int i = start + t; i < end; i += 256) {
    uint2 r = rec[i];
    int lp = atomicAdd(&off[r.x - nbase], 1);
    epack[start + lp] = r.y;
  }
}

// ---------------- fp16 gather aggregation ----------------
// agg128x: XCD-sliced gather. half = (blockIdx>>2)&1 -> under round-robin
// blockIdx%8 -> XCD mapping, XCDs 0-3 only touch cache line 0 (cols 0-63) of
// every x-row, XCDs 4-7 only line 1. Per-XCD distinct-line fetch halves:
// 177MB -> ~89MB compulsory. Wave shape = proven eighth-split, 2-deep.
// Coverage: node = (bid>>3)*16 + (bid&3)*4 + wave, half in {0,1}; grid 50000.
__global__ __launch_bounds__(256) void agg128x_kernel(
    const int* __restrict__ row_ptr, const unsigned int* __restrict__ epack,
    const unsigned short* __restrict__ x, unsigned short* __restrict__ agg)
{
  int bid = blockIdx.x;
  int half = (bid >> 2) & 1;
  int node = (bid >> 3) * 16 + (bid & 3) * 4 + (threadIdx.x >> 6);
  int lane = threadIdx.x & 63;
  if (node >= NNODES) return;
  int q = lane >> 3, sl = lane & 7;
  int colbase = half * 64;
  int s = row_ptr[node], e = row_ptr[node + 1];
  __half2 acch[4];
#pragma unroll
  for (int k = 0; k < 4; k++) acch[k] = __half2half2(__ushort_as_half(0));

  union HU { ushort8 u; __half2 h[4]; };
  const unsigned short* xc = x + colbase;
  for (int i = s + q; i < e; i += 16) {
    unsigned int p0 = epack[i];
    unsigned int p1 = (i + 8 < e) ? epack[i + 8] : 0u;
    int s0, s1; __half2 wA, wB;
    unpack_edge_h(p0, s0, wA);
    unpack_edge_h(p1, s1, wB);
    HU r0, r1;
    r0.u = *(const ushort8*)(xc + (size_t)s0 * 128 + sl * 8);
    r1.u = *(const ushort8*)(xc + (size_t)s1 * 128 + sl * 8);
#pragma unroll
    for (int k = 0; k < 4; k++) {
      acch[k] = __hfma2(wA, r0.h[k], acch[k]);
      acch[k] = __hfma2(wB, r1.h[k], acch[k]);
    }
  }
  float acc[8];
#pragma unroll
  for (int k = 0; k < 4; k++) {
    acc[2 * k]     = __low2float(acch[k]);
    acc[2 * k + 1] = __high2float(acch[k]);
  }
#pragma unroll
  for (int j = 0; j < 8; j++) {
    acc[j] += __shfl_xor(acc[j], 8, 64);
    acc[j] += __shfl_xor(acc[j], 16, 64);
    acc[j] += __shfl_xor(acc[j], 32, 64);
  }
  if (q == 0) {
    ushort8 o;
#pragma unroll
    for (int j = 0; j < 8; j++) o[j] = f2h(acc[j]);
    *(ushort8*)(agg + (size_t)node * 128 + colbase + sl * 8) = o;
  }
}

// agg64: wave per node, eighth-split, 2-deep unroll, packed fp16 math.
// (64-dim row = one 128B line -> XCD slicing cannot reduce fetch; unchanged.)
__global__ __launch_bounds__(256) void agg64_kernel(
    const int* __restrict__ row_ptr, const unsigned int* __restrict__ epack,
    const unsigned short* __restrict__ x, unsigned short* __restrict__ agg)
{
  int node = blockIdx.x * 4 + (threadIdx.x >> 6);
  int lane = threadIdx.x & 63;
  if (node >= NNODES) return;
  int q = lane >> 3, sl = lane & 7;
  int s = row_ptr[node], e = row_ptr[node + 1];
  __half2 acch[4];
#pragma unroll
  for (int k = 0; k < 4; k++) acch[k] = __half2half2(__ushort_as_half(0));

  union HU { ushort8 u; __half2 h[4]; };
  for (int i = s + q; i < e; i += 16) {
    unsigned int p0 = epack[i];
    unsigned int p1 = (i + 8 < e) ? epack[i + 8] : 0u;
    int s0, s1; __half2 wA, wB;
    unpack_edge_h(p0, s0, wA);
    unpack_edge_h(p1, s1, wB);
    HU r0, r1;
    r0.u = *(const ushort8*)(x + (size_t)s0 * 64 + sl * 8);
    r1.u = *(const ushort8*)(x + (size_t)s1 * 64 + sl * 8);
#pragma unroll
    for (int k = 0; k < 4; k++) {
      acch[k] = __hfma2(wA, r0.h[k], acch[k]);
      acch[k] = __hfma2(wB, r1.h[k], acch[k]);
    }
  }
  float acc[8];
#pragma unroll
  for (int k = 0; k < 4; k++) {
    acc[2 * k]     = __low2float(acch[k]);
    acc[2 * k + 1] = __high2float(acch[k]);
  }
#pragma unroll
  for (int j = 0; j < 8; j++) {
    acc[j] += __shfl_xor(acc[j], 8, 64);
    acc[j] += __shfl_xor(acc[j], 16, 64);
    acc[j] += __shfl_xor(acc[j], 32, 64);
  }
  if (q == 0) {
    ushort8 o;
#pragma unroll
    for (int j = 0; j < 8; j++) o[j] = f2h(acc[j]);
    *(ushort8*)(agg + (size_t)node * 64 + sl * 8) = o;
  }
}

// ---------------- LDS-free MFMA fp16 GEMM ----------------
template <int KDIM, int HOUT, int MT, bool DUAL, bool RELU>
__global__ __launch_bounds__(256) void mfma_gemm(
    const unsigned short* __restrict__ A1, const unsigned short* __restrict__ W1,
    const unsigned short* __restrict__ A2, const unsigned short* __restrict__ W2,
    const float* __restrict__ bias, unsigned short* __restrict__ out)
{
  constexpr int NT2 = HOUT / 16;
  constexpr int KC = KDIM / 32;
  const int wave = threadIdx.x >> 6, lane = threadIdx.x & 63;
  const int quad = lane >> 4, l16 = lane & 15;
  const int n0 = (blockIdx.x * 4 + wave) * (MT * 16);

  f32x4 acc[MT][NT2];
#pragma unroll
  for (int m = 0; m < MT; m++)
#pragma unroll
    for (int t = 0; t < NT2; t++) acc[m][t] = (f32x4){0.f, 0.f, 0.f, 0.f};

  int nodes[MT];
#pragma unroll
  for (int m = 0; m < MT; m++) {
    int nd = n0 + m * 16 + l16;
    nodes[m] = nd < NNODES ? nd : NNODES - 1;
  }

#pragma unroll
  for (int c = 0; c < KC; c++) {
    f16x8 bfr[NT2];
#pragma unroll
    for (int t = 0; t < NT2; t++)
      bfr[t] = *(const f16x8*)(W1 + ((size_t)(c * 4 + quad) * HOUT + t * 16 + l16) * 8);
#pragma unroll
    for (int m = 0; m < MT; m++) {
      f16x8 af = *(const f16x8*)(A1 + (size_t)nodes[m] * KDIM + c * 32 + quad * 8);
#pragma unroll
      for (int t = 0; t < NT2; t++)
        acc[m][t] = __builtin_amdgcn_mfma_f32_16x16x32_f16(af, bfr[t], acc[m][t], 0, 0, 0);
    }
    if (DUAL) {
#pragma unroll
      for (int t = 0; t < NT2; t++)
        bfr[t] = *(const f16x8*)(W2 + ((size_t)(c * 4 + quad) * HOUT + t * 16 + l16) * 8);
#pragma unroll
      for (int m = 0; m < MT; m++) {
        f16x8 af = *(const f16x8*)(A2 + (size_t)nodes[m] * KDIM + c * 32 + quad * 8);
#pragma unroll
        for (int t = 0; t < NT2; t++)
          acc[m][t] = __builtin_amdgcn_mfma_f32_16x16x32_f16(af, bfr[t], acc[m][t], 0, 0, 0);
      }
    }
  }

#pragma unroll
  for (int m = 0; m < MT; m++) {
    int rowbase = n0 + m * 16 + quad * 4;
#pragma unroll
    for (int t = 0; t < NT2; t++) {
      float b = bias[t * 16 + l16];
#pragma unroll
      for (int r = 0; r < 4; r++) {
        int nd = rowbase + r;
        if (nd < NNODES) {
          float v = acc[m][t][r] + b;
          if (RELU) v = fmaxf(v, 0.f);
          out[(size_t)nd * HOUT + t * 16 + l16] = f2h(v);
        }
      }
    }
  }
}

// ---------------- readout: per-graph block reduction ----------------
__global__ __launch_bounds__(256) void readout_reduce_kernel(
    const unsigned short* __restrict__ h, const float* __restrict__ Wr2,
    const float* __restrict__ br2, const int* __restrict__ gptr,
    float* __restrict__ out)
{
  __shared__ float wsum[4];
  int g = blockIdx.x;
  int s = gptr[g], e = gptr[g + 1];
  int wave = threadIdx.x >> 6, lane = threadIdx.x & 63;
  float w2 = Wr2[lane];
  float acc = 0.f;
  for (int n = s + wave; n < e; n += 4)
    acc += h2f(h[(size_t)n * 64 + lane]) * w2;
#pragma unroll
  for (int off = 32; off >= 1; off >>= 1) acc += __shfl_xor(acc, off, 64);
  if (lane == 0) wsum[wave] = acc;
  __syncthreads();
  if (threadIdx.x == 0) {
    float cnt = (float)(e - s);
    float sum = wsum[0] + wsum[1] + wsum[2] + wsum[3] + cnt * br2[0];
    out[g] = sum / fmaxf(cnt, 1.f);
  }
}

// ---------------- launch ----------------
extern "C" void kernel_launch(void* const* d_in, const int* in_sizes, int n_in,
                              void* d_out, int out_size, void* d_ws, size_t ws_size,
                              hipStream_t stream)
{
  const float* x      = (const float*)d_in[0];
  const int*   ei     = (const int*)d_in[1];
  const float* ew     = (const float*)d_in[2];
  const int*   batch  = (const int*)d_in[3];
  const float* Wroot0 = (const float*)d_in[4];
  const float* Wrel0  = (const float*)d_in[5];
  const float* b0     = (const float*)d_in[6];
  const float* WrootR = (const float*)d_in[7];
  const float* WrelR  = (const float*)d_in[8];
  const float* bR     = (const float*)d_in[9];
  const float* Wr1    = (const float*)d_in[10];
  const float* br1    = (const float*)d_in[11];
  const float* Wr2    = (const float*)d_in[12];
  const float* br2    = (const float*)d_in[13];

  char* ws = (char*)d_ws;
  unsigned short* wp   = (unsigned short*)ws;                 // 122880 fp16, pad to 131072
  unsigned short* xb   = wp + 131072;                         // N*64 fp16
  unsigned short* agg0 = xb + (size_t)NNODES * 64;            // N*64 fp16 (layer-0 agg)
  unsigned short* bufA = agg0 + (size_t)NNODES * 64;          // N*128 fp16
  unsigned short* bufB = bufA + (size_t)NNODES * 128;         // N*128 fp16
  unsigned short* hbuf = bufB + (size_t)NNODES * 128;         // N*64 fp16
  int*  cnt      = (int*)(hbuf + (size_t)NNODES * 64);        // NBE ints (~600KB)
  int*  rowsum   = cnt + ((NBE + 63) & ~63);
  int*  rowbase  = rowsum + NBUCKET + 1;
  int*  row_ptr  = rowbase + NBUCKET + 1;
  int*  gptr     = row_ptr + NNODES + 2;
  unsigned int* epack = (unsigned int*)(gptr + NGRAPH + 2);   // E uint = 6.4MB
  // rec aliases bufA (12.8MB <= 25.6MB); bufA first written by layer-1 agg,
  // long after bucket_fill_kernel has consumed rec.
  uint2* rec = (uint2*)bufA;

  const unsigned short* pWrel0  = wp;
  const unsigned short* pWroot0 = wp + 8192;
  const unsigned short* pWrelR  = wp + 16384;
  const unsigned short* pWrootR = wp + 65536;
  const unsigned short* pWr1    = wp + 114688;

  // fused setup: cvt_x | prepack | gptr | bucket_count
  setup_kernel<<<SB_TOTAL, 256, 0, stream>>>(
      x, xb, Wrel0, Wroot0, WrelR, WrootR, Wr1, wp, batch, gptr, ei, cnt);

  // bucketized CSR build (by dst)
  row_scan_kernel<<<NBUCKET, 512, 0, stream>>>(cnt, rowsum);
  rowbase_scan_kernel<<<1, 512, 0, stream>>>(rowsum, rowbase);
  bucket_scatter_kernel<<<NCHUNK, 256, 0, stream>>>(ei, ew, cnt, rowbase, rec);
  bucket_fill_kernel<<<NBUCKET, 256, 0, stream>>>(rowbase, rec, epack, row_ptr);

  // layer 0: 64 -> 128
  agg64_kernel<<<(NNODES + 3) / 4, 256, 0, stream>>>(row_ptr, epack, xb, agg0);
  mfma_gemm<64, 128, 2, true, false><<<(NNODES + 127) / 128, 256, 0, stream>>>(
      agg0, pWrel0, xb, pWroot0, b0, bufB);

  // layers 1..3: 128 -> 128 (XCD-sliced gather, grid = NNODES/16*8 = 50000)
  unsigned short* bufs[2] = { bufB, bufA };
  for (int l = 0; l < 3; l++) {
    unsigned short* in  = bufs[l & 1];
    unsigned short* agg = bufs[(l & 1) ^ 1];
    agg128x_kernel<<<(NNODES / 16) * 8, 256, 0, stream>>>(row_ptr, epack, in, agg);
    mfma_gemm<128, 128, 2, true, false><<<(NNODES + 127) / 128, 256, 0, stream>>>(
        agg, pWrelR + l * 16384, in, pWrootR + l * 16384, bR + l * 128, agg);
  }
  // y3 in bufA

  // readout (split, atomic-free: GEMM -> hbuf -> per-graph reduce)
  mfma_gemm<128, 64, 4, false, true><<<(NNODES + 255) / 256, 256, 0, stream>>>(
      bufA, pWr1, nullptr, nullptr, br1, hbuf);
  readout_reduce_kernel<<<NGRAPH, 256, 0, stream>>>(hbuf, Wr2, br2, gptr, (float*)d_out);
}

// Round 14
// 480.419 us; speedup vs baseline: 1.1123x; 1.0831x over previous
//
#include <hip/hip_runtime.h>
#include <hip/hip_fp16.h>
#include <cstdint>
#include <cstddef>

#define NNODES 100000
#define NEDGES 1600000
#define NGRAPH 1024

// bucketized CSR build
#define BK 256                             // nodes per bucket (dst >> 8)
#define NBUCKET 391                        // ceil(NNODES / BK)
#define CHUNK 4096
#define NCHUNK 391                         // ceil(NEDGES / CHUNK)
#define NBE (NBUCKET * NCHUNK)             // 152881 count-matrix entries

// setup_kernel block ranges
#define SB_CVT 6250                        // NNODES*64/4/256
#define SB_PRE (SB_CVT + 60)
#define SB_GPTR (SB_PRE + 391)
#define SB_CNT (SB_GPTR + NCHUNK)
#define SB_TOTAL SB_CNT

typedef __attribute__((ext_vector_type(8))) unsigned short ushort8;
typedef __attribute__((ext_vector_type(8))) _Float16 f16x8;
typedef __attribute__((ext_vector_type(4))) float f32x4;

__device__ inline unsigned short f2h(float f) {
  return __half_as_ushort(__float2half_rn(f));
}
__device__ inline float h2f(unsigned short u) {
  return __half2float(__ushort_as_half(u));
}
// packed edge: (src << 15) | (fp16(weight) >> 1)   [weight >= 0 so sign bit = 0]
__device__ inline unsigned int pack_edge(int src, float w) {
  unsigned short hb = __half_as_ushort(__float2half_rn(w));
  return ((unsigned int)src << 15) | ((unsigned int)hb >> 1);
}
__device__ inline void unpack_edge_h(unsigned int p, int& src, __half2& w2) {
  src = (int)(p >> 15);
  __half wh = __ushort_as_half((unsigned short)((p & 0x7fffu) << 1));
  w2 = __half2half2(wh);
}

// ---------------- fused setup: cvt_x | prepack | gptr | bucket_count ----------------
__global__ __launch_bounds__(256) void setup_kernel(
    const float* __restrict__ x, unsigned short* __restrict__ xb,
    const float* __restrict__ Wrel0, const float* __restrict__ Wroot0,
    const float* __restrict__ WrelR, const float* __restrict__ WrootR,
    const float* __restrict__ Wr1, unsigned short* __restrict__ wp,
    const int* __restrict__ batch, int* __restrict__ gptr,
    const int* __restrict__ ei, int* __restrict__ cnt)
{
  __shared__ int hist[NBUCKET];
  int blk = blockIdx.x;
  if (blk < SB_CVT) {
    int i = blk * 256 + threadIdx.x;
    float4 v = *(const float4*)(x + (size_t)i * 4);
    ushort4 o;
    o.x = f2h(v.x); o.y = f2h(v.y); o.z = f2h(v.z); o.w = f2h(v.w);
    *(ushort4*)(xb + (size_t)i * 4) = o;
  } else if (blk < SB_PRE) {
    int g = (blk - SB_CVT) * 256 + threadIdx.x;
    if (g >= 15360) return;
    const float* src; int H, K, r; unsigned short* out;
    if (g < 1024)       { src = Wrel0;  H = 128; K = 64;  r = g;        out = wp + r * 8; }
    else if (g < 2048)  { src = Wroot0; H = 128; K = 64;  r = g - 1024; out = wp + 8192 + r * 8; }
    else if (g < 8192)  { int m = g - 2048; int l = m / 2048; r = m % 2048;
                          src = WrelR + l * 16384;  H = 128; K = 128;
                          out = wp + 16384 + l * 16384 + r * 8; }
    else if (g < 14336) { int m = g - 8192; int l = m / 2048; r = m % 2048;
                          src = WrootR + l * 16384; H = 128; K = 128;
                          out = wp + 65536 + l * 16384 + r * 8; }
    else                { src = Wr1;    H = 64;  K = 128; r = g - 14336; out = wp + 114688 + r * 8; }
    int n = r % H, k8 = r / H;
    const float* s = src + (size_t)n * K + k8 * 8;
#pragma unroll
    for (int j = 0; j < 8; j++) out[j] = f2h(s[j]);
  } else if (blk < SB_GPTR) {
    int i = (blk - SB_PRE) * 256 + threadIdx.x;
    if (i >= NNODES) return;
    int b = batch[i];
    int bn = (i + 1 < NNODES) ? batch[i + 1] : NGRAPH;
    for (int g = b + 1; g <= bn; g++) gptr[g] = i + 1;
    if (i == 0) for (int g = 0; g <= b; g++) gptr[g] = 0;
  } else {
    int chunk = blk - SB_GPTR;
    for (int i = threadIdx.x; i < NBUCKET; i += 256) hist[i] = 0;
    __syncthreads();
    int base = chunk * CHUNK;
    for (int t = threadIdx.x; t < CHUNK; t += 256) {
      int e = base + t;
      if (e < NEDGES) atomicAdd(&hist[ei[NEDGES + e] >> 8], 1);
    }
    __syncthreads();
    for (int i = threadIdx.x; i < NBUCKET; i += 256)
      cnt[i * NCHUNK + chunk] = hist[i];
  }
}

// ---------------- bucketized CSR build ----------------
__global__ __launch_bounds__(512) void row_scan_kernel(
    int* __restrict__ cnt, int* __restrict__ rowsum)
{
  __shared__ int s[512];
  int b = blockIdx.x, t = threadIdx.x;
  int v = (t < NCHUNK) ? cnt[b * NCHUNK + t] : 0;
  s[t] = v;
  __syncthreads();
#pragma unroll
  for (int off = 1; off < 512; off <<= 1) {
    int u = (t >= off) ? s[t - off] : 0;
    __syncthreads();
    s[t] += u;
    __syncthreads();
  }
  if (t < NCHUNK) cnt[b * NCHUNK + t] = s[t] - v;
  if (t == 511) rowsum[b] = s[511];
}

__global__ __launch_bounds__(512) void rowbase_scan_kernel(
    const int* __restrict__ rowsum, int* __restrict__ rowbase)
{
  __shared__ int s[512];
  int t = threadIdx.x;
  int v = (t < NBUCKET) ? rowsum[t] : 0;
  s[t] = v;
  __syncthreads();
#pragma unroll
  for (int off = 1; off < 512; off <<= 1) {
    int u = (t >= off) ? s[t - off] : 0;
    __syncthreads();
    s[t] += u;
    __syncthreads();
  }
  if (t < NBUCKET) rowbase[t] = s[t] - v;
  if (t == 511) rowbase[NBUCKET] = s[511];   // == NEDGES
}

__global__ __launch_bounds__(256) void bucket_scatter_kernel(
    const int* __restrict__ ei, const float* __restrict__ ew,
    const int* __restrict__ cnt, const int* __restrict__ rowbase,
    uint2* __restrict__ rec)
{
  __shared__ int pos[NBUCKET];
  for (int i = threadIdx.x; i < NBUCKET; i += 256)
    pos[i] = rowbase[i] + cnt[i * NCHUNK + blockIdx.x];
  __syncthreads();
  int base = blockIdx.x * CHUNK;
  for (int t = threadIdx.x; t < CHUNK; t += 256) {
    int e = base + t;
    if (e < NEDGES) {
      int d = ei[NEDGES + e];
      int p = atomicAdd(&pos[d >> 8], 1);
      rec[p] = make_uint2((unsigned int)d, pack_edge(ei[e], ew[e]));
    }
  }
}

__global__ __launch_bounds__(256) void bucket_fill_kernel(
    const int* __restrict__ rowbase, const uint2* __restrict__ rec,
    unsigned int* __restrict__ epack, int* __restrict__ row_ptr)
{
  __shared__ int off[BK];
  __shared__ int s[256];
  int b = blockIdx.x, t = threadIdx.x;
  int start = rowbase[b];
  int end = rowbase[b + 1];
  int nbase = b * BK;
  off[t] = 0;
  __syncthreads();
  for (int i = start + t; i < end; i += 256)
    atomicAdd(&off[rec[i].x - nbase], 1);
  __syncthreads();
  int v = off[t];
  s[t] = v;
  __syncthreads();
#pragma unroll
  for (int o = 1; o < 256; o <<= 1) {
    int u = (t >= o) ? s[t - o] : 0;
    __syncthreads();
    s[t] += u;
    __syncthreads();
  }
  int ex = s[t] - v;
  int g = nbase + t;
  if (g <= NNODES) row_ptr[g] = start + ex;   // g==NNODES -> start+ex == NEDGES
  __syncthreads();
  off[t] = ex;
  __syncthreads();
  for (int i = start + t; i < end; i += 256) {
    uint2 r = rec[i];
    int lp = atomicAdd(&off[r.x - nbase], 1);
    epack[start + lp] = r.y;
  }
}

// ---------------- fp16 gather aggregation (R11-proven: quarter-split, 4-deep) ----------------
__global__ __launch_bounds__(256) void agg128_kernel(
    const int* __restrict__ row_ptr, const unsigned int* __restrict__ epack,
    const unsigned short* __restrict__ x, unsigned short* __restrict__ agg)
{
  int node = blockIdx.x * 4 + (threadIdx.x >> 6);
  int lane = threadIdx.x & 63;
  if (node >= NNODES) return;
  int q = lane >> 4, sl = lane & 15;
  int s = row_ptr[node], e = row_ptr[node + 1];
  __half2 acch[4];
#pragma unroll
  for (int k = 0; k < 4; k++) acch[k] = __half2half2(__ushort_as_half(0));

  union HU { ushort8 u; __half2 h[4]; };
  for (int i = s + q; i < e; i += 16) {
    unsigned int p0 = epack[i];
    unsigned int p1 = (i + 4  < e) ? epack[i + 4]  : 0u;
    unsigned int p2 = (i + 8  < e) ? epack[i + 8]  : 0u;
    unsigned int p3 = (i + 12 < e) ? epack[i + 12] : 0u;
    int s0, s1, s2, s3; __half2 wA, wB, wC, wD;
    unpack_edge_h(p0, s0, wA);
    unpack_edge_h(p1, s1, wB);
    unpack_edge_h(p2, s2, wC);
    unpack_edge_h(p3, s3, wD);
    HU r0, r1, r2, r3;
    r0.u = *(const ushort8*)(x + (size_t)s0 * 128 + sl * 8);
    r1.u = *(const ushort8*)(x + (size_t)s1 * 128 + sl * 8);
    r2.u = *(const ushort8*)(x + (size_t)s2 * 128 + sl * 8);
    r3.u = *(const ushort8*)(x + (size_t)s3 * 128 + sl * 8);
#pragma unroll
    for (int k = 0; k < 4; k++) {
      acch[k] = __hfma2(wA, r0.h[k], acch[k]);
      acch[k] = __hfma2(wB, r1.h[k], acch[k]);
      acch[k] = __hfma2(wC, r2.h[k], acch[k]);
      acch[k] = __hfma2(wD, r3.h[k], acch[k]);
    }
  }
  float acc[8];
#pragma unroll
  for (int k = 0; k < 4; k++) {
    acc[2 * k]     = __low2float(acch[k]);
    acc[2 * k + 1] = __high2float(acch[k]);
  }
#pragma unroll
  for (int j = 0; j < 8; j++) {
    acc[j] += __shfl_xor(acc[j], 16, 64);
    acc[j] += __shfl_xor(acc[j], 32, 64);
  }
  if (q == 0) {
    ushort8 o;
#pragma unroll
    for (int j = 0; j < 8; j++) o[j] = f2h(acc[j]);
    *(ushort8*)(agg + (size_t)node * 128 + sl * 8) = o;
  }
}

// agg64: wave per node, eighth-split, 2-deep unroll, packed fp16 math.
__global__ __launch_bounds__(256) void agg64_kernel(
    const int* __restrict__ row_ptr, const unsigned int* __restrict__ epack,
    const unsigned short* __restrict__ x, unsigned short* __restrict__ agg)
{
  int node = blockIdx.x * 4 + (threadIdx.x >> 6);
  int lane = threadIdx.x & 63;
  if (node >= NNODES) return;
  int q = lane >> 3, sl = lane & 7;
  int s = row_ptr[node], e = row_ptr[node + 1];
  __half2 acch[4];
#pragma unroll
  for (int k = 0; k < 4; k++) acch[k] = __half2half2(__ushort_as_half(0));

  union HU { ushort8 u; __half2 h[4]; };
  for (int i = s + q; i < e; i += 16) {
    unsigned int p0 = epack[i];
    unsigned int p1 = (i + 8 < e) ? epack[i + 8] : 0u;
    int s0, s1; __half2 wA, wB;
    unpack_edge_h(p0, s0, wA);
    unpack_edge_h(p1, s1, wB);
    HU r0, r1;
    r0.u = *(const ushort8*)(x + (size_t)s0 * 64 + sl * 8);
    r1.u = *(const ushort8*)(x + (size_t)s1 * 64 + sl * 8);
#pragma unroll
    for (int k = 0; k < 4; k++) {
      acch[k] = __hfma2(wA, r0.h[k], acch[k]);
      acch[k] = __hfma2(wB, r1.h[k], acch[k]);
    }
  }
  float acc[8];
#pragma unroll
  for (int k = 0; k < 4; k++) {
    acc[2 * k]     = __low2float(acch[k]);
    acc[2 * k + 1] = __high2float(acch[k]);
  }
#pragma unroll
  for (int j = 0; j < 8; j++) {
    acc[j] += __shfl_xor(acc[j], 8, 64);
    acc[j] += __shfl_xor(acc[j], 16, 64);
    acc[j] += __shfl_xor(acc[j], 32, 64);
  }
  if (q == 0) {
    ushort8 o;
#pragma unroll
    for (int j = 0; j < 8; j++) o[j] = f2h(acc[j]);
    *(ushort8*)(agg + (size_t)node * 64 + sl * 8) = o;
  }
}

// ---------------- LDS-free MFMA fp16 GEMM ----------------
template <int KDIM, int HOUT, int MT, bool DUAL, bool RELU>
__global__ __launch_bounds__(256) void mfma_gemm(
    const unsigned short* __restrict__ A1, const unsigned short* __restrict__ W1,
    const unsigned short* __restrict__ A2, const unsigned short* __restrict__ W2,
    const float* __restrict__ bias, unsigned short* __restrict__ out)
{
  constexpr int NT2 = HOUT / 16;
  constexpr int KC = KDIM / 32;
  const int wave = threadIdx.x >> 6, lane = threadIdx.x & 63;
  const int quad = lane >> 4, l16 = lane & 15;
  const int n0 = (blockIdx.x * 4 + wave) * (MT * 16);

  f32x4 acc[MT][NT2];
#pragma unroll
  for (int m = 0; m < MT; m++)
#pragma unroll
    for (int t = 0; t < NT2; t++) acc[m][t] = (f32x4){0.f, 0.f, 0.f, 0.f};

  int nodes[MT];
#pragma unroll
  for (int m = 0; m < MT; m++) {
    int nd = n0 + m * 16 + l16;
    nodes[m] = nd < NNODES ? nd : NNODES - 1;
  }

#pragma unroll
  for (int c = 0; c < KC; c++) {
    f16x8 bfr[NT2];
#pragma unroll
    for (int t = 0; t < NT2; t++)
      bfr[t] = *(const f16x8*)(W1 + ((size_t)(c * 4 + quad) * HOUT + t * 16 + l16) * 8);
#pragma unroll
    for (int m = 0; m < MT; m++) {
      f16x8 af = *(const f16x8*)(A1 + (size_t)nodes[m] * KDIM + c * 32 + quad * 8);
#pragma unroll
      for (int t = 0; t < NT2; t++)
        acc[m][t] = __builtin_amdgcn_mfma_f32_16x16x32_f16(af, bfr[t], acc[m][t], 0, 0, 0);
    }
    if (DUAL) {
#pragma unroll
      for (int t = 0; t < NT2; t++)
        bfr[t] = *(const f16x8*)(W2 + ((size_t)(c * 4 + quad) * HOUT + t * 16 + l16) * 8);
#pragma unroll
      for (int m = 0; m < MT; m++) {
        f16x8 af = *(const f16x8*)(A2 + (size_t)nodes[m] * KDIM + c * 32 + quad * 8);
#pragma unroll
        for (int t = 0; t < NT2; t++)
          acc[m][t] = __builtin_amdgcn_mfma_f32_16x16x32_f16(af, bfr[t], acc[m][t], 0, 0, 0);
      }
    }
  }

#pragma unroll
  for (int m = 0; m < MT; m++) {
    int rowbase = n0 + m * 16 + quad * 4;
#pragma unroll
    for (int t = 0; t < NT2; t++) {
      float b = bias[t * 16 + l16];
#pragma unroll
      for (int r = 0; r < 4; r++) {
        int nd = rowbase + r;
        if (nd < NNODES) {
          float v = acc[m][t][r] + b;
          if (RELU) v = fmaxf(v, 0.f);
          out[(size_t)nd * HOUT + t * 16 + l16] = f2h(v);
        }
      }
    }
  }
}

// ---------------- readout GEMM: 128->64 + ReLU + dot(Wr2) -> per-node scalar ----------------
// Same epilogue reduction as R4/R9 (validated) but STORES pnode[nd] (no atomics).
__global__ __launch_bounds__(256) void readout_gemm_kernel(
    const unsigned short* __restrict__ A1, const unsigned short* __restrict__ W1,
    const float* __restrict__ br1, const float* __restrict__ Wr2,
    float* __restrict__ pnode)
{
  constexpr int NT2 = 4, KC = 4, MT = 4;
  const int wave = threadIdx.x >> 6, lane = threadIdx.x & 63;
  const int quad = lane >> 4, l16 = lane & 15;
  const int n0 = (blockIdx.x * 4 + wave) * (MT * 16);

  f32x4 acc[MT][NT2];
#pragma unroll
  for (int m = 0; m < MT; m++)
#pragma unroll
    for (int t = 0; t < NT2; t++) acc[m][t] = (f32x4){0.f, 0.f, 0.f, 0.f};

  int nodes[MT];
#pragma unroll
  for (int m = 0; m < MT; m++) {
    int nd = n0 + m * 16 + l16;
    nodes[m] = nd < NNODES ? nd : NNODES - 1;
  }

#pragma unroll
  for (int c = 0; c < KC; c++) {
    f16x8 bfr[NT2];
#pragma unroll
    for (int t = 0; t < NT2; t++)
      bfr[t] = *(const f16x8*)(W1 + ((size_t)(c * 4 + quad) * 64 + t * 16 + l16) * 8);
#pragma unroll
    for (int m = 0; m < MT; m++) {
      f16x8 af = *(const f16x8*)(A1 + (size_t)nodes[m] * 128 + c * 32 + quad * 8);
#pragma unroll
      for (int t = 0; t < NT2; t++)
        acc[m][t] = __builtin_amdgcn_mfma_f32_16x16x32_f16(af, bfr[t], acc[m][t], 0, 0, 0);
    }
  }

  float bv[NT2], wv[NT2];
#pragma unroll
  for (int t = 0; t < NT2; t++) {
    bv[t] = br1[t * 16 + l16];
    wv[t] = Wr2[t * 16 + l16];
  }
#pragma unroll
  for (int m = 0; m < MT; m++) {
    int rowbase = n0 + m * 16 + quad * 4;
#pragma unroll
    for (int r = 0; r < 4; r++) {
      float p = 0.f;
#pragma unroll
      for (int t = 0; t < NT2; t++)
        p += fmaxf(acc[m][t][r] + bv[t], 0.f) * wv[t];
      p += __shfl_xor(p, 1, 64);
      p += __shfl_xor(p, 2, 64);
      p += __shfl_xor(p, 4, 64);
      p += __shfl_xor(p, 8, 64);
      int nd = rowbase + r;
      if (l16 == 0 && nd < NNODES) pnode[nd] = p;
    }
  }
}

// ---------------- readout: per-graph scalar segment reduction ----------------
__global__ __launch_bounds__(256) void readout_reduce_kernel(
    const float* __restrict__ pnode, const float* __restrict__ br2,
    const int* __restrict__ gptr, float* __restrict__ out)
{
  __shared__ float wsum[4];
  int g = blockIdx.x;
  int s = gptr[g], e = gptr[g + 1];
  int wave = threadIdx.x >> 6, lane = threadIdx.x & 63;
  float acc = 0.f;
  for (int n = s + threadIdx.x; n < e; n += 256) acc += pnode[n];
#pragma unroll
  for (int off = 32; off >= 1; off >>= 1) acc += __shfl_xor(acc, off, 64);
  if (lane == 0) wsum[wave] = acc;
  __syncthreads();
  if (threadIdx.x == 0) {
    float cnt = (float)(e - s);
    float sum = wsum[0] + wsum[1] + wsum[2] + wsum[3] + cnt * br2[0];
    out[g] = sum / fmaxf(cnt, 1.f);
  }
}

// ---------------- launch ----------------
extern "C" void kernel_launch(void* const* d_in, const int* in_sizes, int n_in,
                              void* d_out, int out_size, void* d_ws, size_t ws_size,
                              hipStream_t stream)
{
  const float* x      = (const float*)d_in[0];
  const int*   ei     = (const int*)d_in[1];
  const float* ew     = (const float*)d_in[2];
  const int*   batch  = (const int*)d_in[3];
  const float* Wroot0 = (const float*)d_in[4];
  const float* Wrel0  = (const float*)d_in[5];
  const float* b0     = (const float*)d_in[6];
  const float* WrootR = (const float*)d_in[7];
  const float* WrelR  = (const float*)d_in[8];
  const float* bR     = (const float*)d_in[9];
  const float* Wr1    = (const float*)d_in[10];
  const float* br1    = (const float*)d_in[11];
  const float* Wr2    = (const float*)d_in[12];
  const float* br2    = (const float*)d_in[13];

  char* ws = (char*)d_ws;
  unsigned short* wp   = (unsigned short*)ws;                 // 122880 fp16, pad to 131072
  unsigned short* xb   = wp + 131072;                         // N*64 fp16
  unsigned short* agg0 = xb + (size_t)NNODES * 64;            // N*64 fp16 (layer-0 agg)
  unsigned short* bufA = agg0 + (size_t)NNODES * 64;          // N*128 fp16
  unsigned short* bufB = bufA + (size_t)NNODES * 128;         // N*128 fp16
  float* pnode  = (float*)(bufB + (size_t)NNODES * 128);      // N floats
  int*  cnt      = (int*)(pnode + NNODES + 64);               // NBE ints (~600KB)
  int*  rowsum   = cnt + ((NBE + 63) & ~63);
  int*  rowbase  = rowsum + NBUCKET + 1;
  int*  row_ptr  = rowbase + NBUCKET + 1;
  int*  gptr     = row_ptr + NNODES + 2;
  unsigned int* epack = (unsigned int*)(gptr + NGRAPH + 2);   // E uint = 6.4MB
  // rec aliases bufA (12.8MB <= 25.6MB); bufA first written by layer-1 agg,
  // long after bucket_fill_kernel has consumed rec.
  uint2* rec = (uint2*)bufA;

  const unsigned short* pWrel0  = wp;
  const unsigned short* pWroot0 = wp + 8192;
  const unsigned short* pWrelR  = wp + 16384;
  const unsigned short* pWrootR = wp + 65536;
  const unsigned short* pWr1    = wp + 114688;

  // fused setup: cvt_x | prepack | gptr | bucket_count
  setup_kernel<<<SB_TOTAL, 256, 0, stream>>>(
      x, xb, Wrel0, Wroot0, WrelR, WrootR, Wr1, wp, batch, gptr, ei, cnt);

  // bucketized CSR build (by dst)
  row_scan_kernel<<<NBUCKET, 512, 0, stream>>>(cnt, rowsum);
  rowbase_scan_kernel<<<1, 512, 0, stream>>>(rowsum, rowbase);
  bucket_scatter_kernel<<<NCHUNK, 256, 0, stream>>>(ei, ew, cnt, rowbase, rec);
  bucket_fill_kernel<<<NBUCKET, 256, 0, stream>>>(rowbase, rec, epack, row_ptr);

  // layer 0: 64 -> 128
  agg64_kernel<<<(NNODES + 3) / 4, 256, 0, stream>>>(row_ptr, epack, xb, agg0);
  mfma_gemm<64, 128, 2, true, false><<<(NNODES + 127) / 128, 256, 0, stream>>>(
      agg0, pWrel0, xb, pWroot0, b0, bufB);

  // layers 1..3: 128 -> 128
  unsigned short* bufs[2] = { bufB, bufA };
  for (int l = 0; l < 3; l++) {
    unsigned short* in  = bufs[l & 1];
    unsigned short* agg = bufs[(l & 1) ^ 1];
    agg128_kernel<<<(NNODES + 3) / 4, 256, 0, stream>>>(row_ptr, epack, in, agg);
    mfma_gemm<128, 128, 2, true, false><<<(NNODES + 127) / 128, 256, 0, stream>>>(
        agg, pWrelR + l * 16384, in, pWrootR + l * 16384, bR + l * 128, agg);
  }
  // y3 in bufA

  // readout: GEMM+ReLU+dot -> per-node scalar (atomic-free), then segment reduce
  readout_gemm_kernel<<<(NNODES + 255) / 256, 256, 0, stream>>>(
      bufA, pWr1, br1, Wr2, pnode);
  readout_reduce_kernel<<<NGRAPH, 256, 0, stream>>>(pnode, br2, gptr, (float*)d_out);
}